// Round 6
// baseline (1038.206 us; speedup 1.0000x reference)
//
#include <hip/hip_runtime.h>
#include <hip/hip_bf16.h>

#define B_ 32
#define T_ 512
#define D_ 1024
#define HOP_ 8
#define HID_ 350
#define NEGV -1e30f
#define CH_ 4  // batches per chunk (fp32 fallback path)

typedef __bf16 v8bf __attribute__((ext_vector_type(8)));
typedef float  v4f  __attribute__((ext_vector_type(4)));

__device__ __forceinline__ float fast_sigmoid(float x) {
    return 1.0f / (1.0f + __expf(-x));
}
__device__ __forceinline__ float fast_tanh(float x) {
    return 1.0f - 2.0f / (__expf(2.0f * x) + 1.0f);
}
__device__ __forceinline__ float bf2f(unsigned short u) {
    unsigned x = ((unsigned)u) << 16;
    float f;
    __builtin_memcpy(&f, &x, 4);
    return f;
}
__device__ __forceinline__ unsigned short f2bf(float v) {
    __hip_bfloat16 h = __float2bfloat16(v);
    unsigned short u;
    __builtin_memcpy(&u, &h, 2);
    return u;
}

// ---------------- lengths ----------------
__global__ __launch_bounds__(512) void lengths_k(const float* __restrict__ input,
                                                 int* __restrict__ len) {
    int b = blockIdx.x;
    int t = threadIdx.x;
    int z = (input[((size_t)b * T_ + t) * D_] == 0.0f) ? 1 : 0;
    __shared__ int cnt;
    if (t == 0) cnt = 0;
    __syncthreads();
    unsigned long long m = __ballot(z);
    if ((t & 63) == 0) atomicAdd(&cnt, __popcll(m));
    __syncthreads();
    if (t == 0) len[b] = T_ - cnt;
}

// =================== FAST PATH (bf16 MFMA) ===================

// fp32 -> bf16 rowmajor copy (vector 4)
__global__ __launch_bounds__(256) void convX_k(const float* __restrict__ in,
                                               unsigned short* __restrict__ out) {
    int i = (blockIdx.x * 256 + threadIdx.x) * 4;
    float4 v = *(const float4*)&in[i];
    out[i + 0] = f2bf(v.x);
    out[i + 1] = f2bf(v.y);
    out[i + 2] = f2bf(v.z);
    out[i + 3] = f2bf(v.w);
}

// weight -> tiled bf16 layout [kb][nb][n:128][k:32]  (4096 elems per tile)
// NT=false: W is (K,N) row-major. NT=true: W is (Nreal,K) row-major, zero-pad n>=Nreal.
template <bool NT>
__global__ __launch_bounds__(256) void convW_k(const float* __restrict__ W,
                                               unsigned short* __restrict__ Wp,
                                               int K, int N, int nT, int Nreal) {
    int o = blockIdx.x * 256 + threadIdx.x;
    int tile = o >> 12;          // 128*32 = 4096 elems per tile
    int within = o & 4095;
    int n_l = within >> 5, k_l = within & 31;
    int kb = tile / nT, nbb = tile % nT;
    int n = nbb * 128 + n_l, k = kb * 32 + k_l;
    float v = 0.f;
    if (NT) {
        if (n < Nreal) v = W[(size_t)n * K + k];
    } else {
        v = W[(size_t)k * N + n];
    }
    Wp[o] = f2bf(v);
}

// MFMA GEMM: C = A(M,K) @ B(K,N), 128x128 tile, BK=32, 4 waves of 64x64.
// EPI 0: bf16 store of C^T via LDS transpose -> U't [n][m], row stride ldc (=Mtot).
// EPI 1: tanh epilogue -> fp32 C [m][n] (stride ldc=Nstore), guard col < ldc.
template <int EPI>
__global__ __launch_bounds__(256) void gemm_mfma(
    const unsigned short* __restrict__ A,
    const unsigned short* __restrict__ Bp,
    void* __restrict__ C,
    int K, int nT, int ldc) {
    __shared__ __align__(16) char smem[34816];  // staging 16 KB / C-tile 34 KB
    unsigned short* As = (unsigned short*)smem;
    unsigned short* Bs = (unsigned short*)(smem + 8192);
    const int tid = threadIdx.x;
    const int lane = tid & 63;
    const int wid = __builtin_amdgcn_readfirstlane(tid >> 6);
    const int wm = wid & 1, wn = wid >> 1;
    const int m0 = blockIdx.y * 128;
    const int n0 = blockIdx.x * 128;
    const int nb = blockIdx.x;
    const int quad = lane >> 4;
    const int l15 = lane & 15;

    v4f acc[4][4];
#pragma unroll
    for (int i = 0; i < 4; ++i)
#pragma unroll
        for (int j = 0; j < 4; ++j) acc[i][j] = (v4f)(0.f);

    const int nKB = K >> 5;
    for (int kb = 0; kb < nKB; ++kb) {
        __syncthreads();
        // stage A: 128 rows x 32 k; granule g (16B) -> row g>>2, kpart g&3
#pragma unroll
        for (int p = 0; p < 2; ++p) {
            int g = p * 256 + wid * 64 + lane;
            const unsigned short* gp = A + (size_t)(m0 + (g >> 2)) * K + kb * 32 + (g & 3) * 8;
            int ldsOff = (p * 256 + wid * 64) * 16;
            __builtin_amdgcn_global_load_lds(
                (const __attribute__((address_space(1))) void*)gp,
                (__attribute__((address_space(3))) void*)((char*)As + ldsOff),
                16, 0, 0);
        }
        // stage B: linear copy of pre-tiled 8KB block
        const unsigned short* bt = Bp + (size_t)(kb * nT + nb) * (128 * 32);
#pragma unroll
        for (int p = 0; p < 2; ++p) {
            int g = p * 256 + wid * 64 + lane;
            const unsigned short* gp = bt + g * 8;
            int ldsOff = (p * 256 + wid * 64) * 16;
            __builtin_amdgcn_global_load_lds(
                (const __attribute__((address_space(1))) void*)gp,
                (__attribute__((address_space(3))) void*)((char*)Bs + ldsOff),
                16, 0, 0);
        }
        __syncthreads();
        v8bf af[4], bfr[4];
#pragma unroll
        for (int mi = 0; mi < 4; ++mi)
            af[mi] = *(const v8bf*)&As[(wm * 64 + mi * 16 + l15) * 32 + quad * 8];
#pragma unroll
        for (int ni = 0; ni < 4; ++ni)
            bfr[ni] = *(const v8bf*)&Bs[(wn * 64 + ni * 16 + l15) * 32 + quad * 8];
#pragma unroll
        for (int mi = 0; mi < 4; ++mi)
#pragma unroll
            for (int ni = 0; ni < 4; ++ni)
                acc[mi][ni] = __builtin_amdgcn_mfma_f32_16x16x32_bf16(
                    af[mi], bfr[ni], acc[mi][ni], 0, 0, 0);
    }

    if (EPI == 0) {
        // LDS transpose epilogue -> C^T: Ct row-major [128 n][136] (pad 8 shorts)
        __syncthreads();
        unsigned short* Ct = (unsigned short*)smem;
#pragma unroll
        for (int ni = 0; ni < 4; ++ni) {
            int n_l = wn * 64 + ni * 16 + l15;
#pragma unroll
            for (int mi = 0; mi < 4; ++mi) {
                int m_l = wm * 64 + mi * 16 + quad * 4;
                v4f cc = acc[mi][ni];
                ushort4 pk;
                pk.x = f2bf(cc[0]); pk.y = f2bf(cc[1]);
                pk.z = f2bf(cc[2]); pk.w = f2bf(cc[3]);
                *(ushort4*)&Ct[n_l * 136 + m_l] = pk;
            }
        }
        __syncthreads();
        int row = tid >> 1;          // n_l
        int colH = (tid & 1) << 6;   // m half
        unsigned short* gdst = (unsigned short*)C + (size_t)(n0 + row) * ldc + m0 + colH;
        const unsigned short* lsrc = Ct + row * 136 + colH;
#pragma unroll
        for (int i = 0; i < 8; ++i) {
            uint4 v = *(const uint4*)(lsrc + i * 8);
            *(uint4*)(gdst + i * 8) = v;
        }
    } else {
        const int baseM = m0 + wm * 64;
        const int baseN = n0 + wn * 64;
        float* Cf = (float*)C;
#pragma unroll
        for (int ni = 0; ni < 4; ++ni) {
            int j = baseN + ni * 16 + l15;
            if (j < ldc) {
#pragma unroll
                for (int mi = 0; mi < 4; ++mi) {
                    int m = baseM + mi * 16 + quad * 4;
                    v4f c = acc[mi][ni];
#pragma unroll
                    for (int r = 0; r < 4; ++r)
                        Cf[(size_t)(m + r) * ldc + j] = fast_tanh(c[r]);
                }
            }
        }
    }
}

// Segmented SRU scan (fused 3-phase) over transposed U't [n=3072][m=Mtot].
// U't holds raw preactivations {xt, uf, ur} planes at n = d, 1024+d, 2048+d.
// Block: 512 threads = 64 d x 8 segments; grid = (#batches)*16 d-chunks.
__global__ __launch_bounds__(512) void sru_scan_seg(
    const unsigned short* __restrict__ Ut,
    const float* __restrict__ bias,
    const unsigned short* __restrict__ xres,
    unsigned short* __restrict__ xout,
    int Mtot) {
    int b = blockIdx.x >> 4;
    int d0 = (blockIdx.x & 15) << 6;
    int dl = threadIdx.x & 63;
    int s = threadIdx.x >> 6;
    int d = d0 + dl;
    float bf = bias[d], br = bias[D_ + d];
    size_t mb = (size_t)b * T_;
    const unsigned short* xtp = Ut + (size_t)d * Mtot + mb;
    const unsigned short* ffp = Ut + (size_t)(D_ + d) * Mtot + mb;
    const unsigned short* rrp = Ut + (size_t)(2 * D_ + d) * Mtot + mb;
    const int t0 = s * 64;

    // phase A: per-segment affine composition (a = prod f, b = scan from 0)
    float Aa = 1.f, Bv = 0.f;
    for (int tt = 0; tt < 64; tt += 8) {
        v8bf xtv = *(const v8bf*)&xtp[t0 + tt];
        v8bf fvv = *(const v8bf*)&ffp[t0 + tt];
#pragma unroll
        for (int j = 0; j < 8; ++j) {
            float f = fast_sigmoid((float)fvv[j] + bf);
            Aa *= f;
            Bv = f * Bv + (1.f - f) * (float)xtv[j];
        }
    }
    __shared__ float Asm[8][64], Bsm[8][64], cinS[8][64];
    Asm[s][dl] = Aa;
    Bsm[s][dl] = Bv;
    __syncthreads();
    // phase B: compose 8 segment summaries
    if (threadIdx.x < 64) {
        float c = 0.f;
#pragma unroll
        for (int ss = 0; ss < 8; ++ss) {
            cinS[ss][threadIdx.x] = c;
            c = Asm[ss][threadIdx.x] * c + Bsm[ss][threadIdx.x];
        }
    }
    __syncthreads();
    // phase C: re-scan with correct initial state, emit outputs
    float c = cinS[s][dl];
    const unsigned short* xr = xres + mb * D_ + d;
    unsigned short* ob = xout + mb * D_ + d;
    for (int tt = 0; tt < 64; tt += 8) {
        v8bf xtv = *(const v8bf*)&xtp[t0 + tt];
        v8bf fvv = *(const v8bf*)&ffp[t0 + tt];
        v8bf rvv = *(const v8bf*)&rrp[t0 + tt];
        float xv[8];
#pragma unroll
        for (int j = 0; j < 8; ++j)
            xv[j] = bf2f(xr[(size_t)(t0 + tt + j) * D_]);
#pragma unroll
        for (int j = 0; j < 8; ++j) {
            float f = fast_sigmoid((float)fvv[j] + bf);
            float r = fast_sigmoid((float)rvv[j] + br);
            c = f * c + (1.f - f) * (float)xtv[j];
            float o = r * fast_tanh(c) + (1.f - r) * xv[j];
            ob[(size_t)(t0 + tt + j) * D_] = f2bf(o);
        }
    }
}

// =================== FALLBACK PATH (fp32, chunked; round-2 proven) ===================

template <bool BT, bool DO_TANH>
__global__ __launch_bounds__(256) void gemm64(const float* __restrict__ A,
                                              const float* __restrict__ Bm,
                                              float* __restrict__ C,
                                              int M, int N, int K) {
    __shared__ float Asm[16][64];
    __shared__ float Bsm[16][64];
    const int tid = threadIdx.x;
    const int tx = tid & 15;
    const int ty = tid >> 4;
    const int m0 = blockIdx.y * 64;
    const int n0 = blockIdx.x * 64;
    float acc[4][4] = {};
    const int ar = tid >> 2;
    const int ac = (tid & 3) << 2;

    for (int k0 = 0; k0 < K; k0 += 16) {
        {
            float4 v = *(const float4*)&A[(size_t)(m0 + ar) * K + k0 + ac];
            Asm[ac + 0][ar] = v.x; Asm[ac + 1][ar] = v.y;
            Asm[ac + 2][ar] = v.z; Asm[ac + 3][ar] = v.w;
        }
        if (!BT) {
            int kk = tid >> 4;
            int c4 = (tid & 15) << 2;
            float4 v = *(const float4*)&Bm[(size_t)(k0 + kk) * N + n0 + c4];
            Bsm[kk][c4 + 0] = v.x; Bsm[kk][c4 + 1] = v.y;
            Bsm[kk][c4 + 2] = v.z; Bsm[kk][c4 + 3] = v.w;
        } else {
            int nn = tid >> 2;
            int kk = (tid & 3) << 2;
            int row = n0 + nn;
            if (row < N) {
                float4 v = *(const float4*)&Bm[(size_t)row * K + k0 + kk];
                Bsm[kk + 0][nn] = v.x; Bsm[kk + 1][nn] = v.y;
                Bsm[kk + 2][nn] = v.z; Bsm[kk + 3][nn] = v.w;
            } else {
                Bsm[kk + 0][nn] = 0.f; Bsm[kk + 1][nn] = 0.f;
                Bsm[kk + 2][nn] = 0.f; Bsm[kk + 3][nn] = 0.f;
            }
        }
        __syncthreads();
#pragma unroll
        for (int kk = 0; kk < 16; ++kk) {
            float4 a = *(const float4*)&Asm[kk][ty << 2];
            float4 b = *(const float4*)&Bsm[kk][tx << 2];
            float am[4] = {a.x, a.y, a.z, a.w};
            float bm[4] = {b.x, b.y, b.z, b.w};
#pragma unroll
            for (int i = 0; i < 4; ++i)
#pragma unroll
                for (int j = 0; j < 4; ++j)
                    acc[i][j] += am[i] * bm[j];
        }
        __syncthreads();
    }
#pragma unroll
    for (int i = 0; i < 4; ++i) {
        int row = m0 + (ty << 2) + i;
#pragma unroll
        for (int j = 0; j < 4; ++j) {
            int col = n0 + (tx << 2) + j;
            if (col < N) {
                float v = acc[i][j];
                if (DO_TANH) v = fast_tanh(v);
                C[(size_t)row * N + col] = v;
            }
        }
    }
}

__global__ __launch_bounds__(256) void sru_scan(const float* __restrict__ U,
                                                const float* __restrict__ bias,
                                                const float* __restrict__ xin,
                                                float* __restrict__ xout) {
    int idx = blockIdx.x * 256 + threadIdx.x;
    int b = idx >> 10;
    int d = idx & (D_ - 1);
    float bfv = bias[d], br = bias[D_ + d];
    float c = 0.0f;
    const float* Ub = U + (size_t)b * T_ * (3 * D_);
    const float* xb = xin + (size_t)b * T_ * D_;
    float* ob = xout + (size_t)b * T_ * D_;
    for (int t = 0; t < T_; t += 8) {
        float ux[8], uf[8], ur[8], xv[8];
#pragma unroll
        for (int j = 0; j < 8; ++j) {
            const float* u = Ub + (size_t)(t + j) * (3 * D_);
            ux[j] = u[d];
            uf[j] = u[D_ + d];
            ur[j] = u[2 * D_ + d];
            xv[j] = xb[(size_t)(t + j) * D_ + d];
        }
#pragma unroll
        for (int j = 0; j < 8; ++j) {
            float f = fast_sigmoid(uf[j] + bfv);
            float r = fast_sigmoid(ur[j] + br);
            c = f * c + (1.0f - f) * ux[j];
            ob[(size_t)(t + j) * D_ + d] = r * fast_tanh(c) + (1.0f - r) * xv[j];
        }
    }
}

// =================== shared tail kernels ===================

__global__ __launch_bounds__(256) void alphas_k(const float* __restrict__ hbar,
                                                const float* __restrict__ ws2,
                                                float* __restrict__ alph) {
    __shared__ float w[HOP_][352];
    for (int i = threadIdx.x; i < HOP_ * HID_; i += 256)
        w[i / HID_][i % HID_] = ws2[i];
    __syncthreads();
    int bt = blockIdx.x * 256 + threadIdx.x;
    const float* hr = hbar + (size_t)bt * HID_;
    float acc[HOP_] = {};
    for (int h = 0; h < HID_; ++h) {
        float hv = hr[h];
#pragma unroll
        for (int k = 0; k < HOP_; ++k) acc[k] += w[k][h] * hv;
    }
    float* ar = alph + (size_t)bt * HOP_;
#pragma unroll
    for (int k = 0; k < HOP_; ++k) ar[k] = acc[k];
}

__global__ __launch_bounds__(256) void softmax_k(const float* __restrict__ alph,
                                                 const int* __restrict__ len,
                                                 float* __restrict__ attn) {
    int b = blockIdx.x >> 3, k = blockIdx.x & 7;
    int L = len[b];
    int t0 = threadIdx.x, t1 = threadIdx.x + 256;
    float v0 = (t0 >= L) ? NEGV : alph[((size_t)b * T_ + t0) * HOP_ + k];
    float v1 = (t1 >= L) ? NEGV : alph[((size_t)b * T_ + t1) * HOP_ + k];
    __shared__ float redm[4];
    __shared__ float reds[4];
    float m = fmaxf(v0, v1);
#pragma unroll
    for (int off = 32; off; off >>= 1) m = fmaxf(m, __shfl_xor(m, off));
    if ((threadIdx.x & 63) == 0) redm[threadIdx.x >> 6] = m;
    __syncthreads();
    m = fmaxf(fmaxf(redm[0], redm[1]), fmaxf(redm[2], redm[3]));
    float e0 = __expf(v0 - m), e1 = __expf(v1 - m);
    float s = e0 + e1;
#pragma unroll
    for (int off = 32; off; off >>= 1) s += __shfl_xor(s, off);
    if ((threadIdx.x & 63) == 0) reds[threadIdx.x >> 6] = s;
    __syncthreads();
    s = reds[0] + reds[1] + reds[2] + reds[3];
    float inv = 1.0f / s;
    float* ar = attn + ((size_t)b * HOP_ + k) * T_;
    ar[t0] = e0 * inv;
    ar[t1] = e1 * inv;
}

// pooled from bf16 x2 (normal [m][d] layout)
__global__ __launch_bounds__(256) void pooled_bf_k(const float* __restrict__ attn,
                                                   const unsigned short* __restrict__ x2b,
                                                   float* __restrict__ pooled) {
    __shared__ float at[HOP_][T_];
    int b = blockIdx.x >> 2;
    int d0 = (blockIdx.x & 3) * 256;
    for (int i = threadIdx.x; i < HOP_ * T_; i += 256)
        at[i >> 9][i & (T_ - 1)] = attn[(size_t)b * HOP_ * T_ + i];
    __syncthreads();
    int d = d0 + threadIdx.x;
    float acc[HOP_] = {};
    const unsigned short* xb = x2b + (size_t)b * T_ * D_ + d;
    for (int t = 0; t < T_; ++t) {
        float xv = bf2f(xb[(size_t)t * D_]);
#pragma unroll
        for (int k = 0; k < HOP_; ++k) acc[k] += at[k][t] * xv;
    }
#pragma unroll
    for (int k = 0; k < HOP_; ++k)
        pooled[((size_t)b * HOP_ + k) * D_ + d] = acc[k];
}

// pooled from fp32 x2 (fallback)
__global__ __launch_bounds__(256) void pooled_k(const float* __restrict__ attn,
                                                const float* __restrict__ x2,
                                                float* __restrict__ pooled) {
    __shared__ float at[HOP_][T_];
    int b = blockIdx.x >> 2;
    int d0 = (blockIdx.x & 3) * 256;
    for (int i = threadIdx.x; i < HOP_ * T_; i += 256)
        at[i >> 9][i & (T_ - 1)] = attn[(size_t)b * HOP_ * T_ + i];
    __syncthreads();
    int d = d0 + threadIdx.x;
    float acc[HOP_] = {};
    const float* xb = x2 + (size_t)b * T_ * D_ + d;
    for (int t = 0; t < T_; ++t) {
        float xv = xb[(size_t)t * D_];
#pragma unroll
        for (int k = 0; k < HOP_; ++k) acc[k] += at[k][t] * xv;
    }
#pragma unroll
    for (int k = 0; k < HOP_; ++k)
        pooled[((size_t)b * HOP_ + k) * D_ + d] = acc[k];
}

__global__ __launch_bounds__(256) void fc_k(const float* __restrict__ pooled,
                                            const float* __restrict__ fcw,
                                            const float* __restrict__ fcb,
                                            float* __restrict__ out) {
    __shared__ float w[8][1028];
    int j0 = blockIdx.x * 8;
    int b = threadIdx.x >> 3, jj = threadIdx.x & 7;
    float acc = 0.0f;
    for (int p0 = 0; p0 < HOP_ * D_; p0 += 1024) {
        __syncthreads();
        for (int i = threadIdx.x * 4; i < 8 * 1024; i += 256 * 4) {
            int r = i >> 10, c = i & 1023;
            *(float4*)&w[r][c] = *(const float4*)&fcw[(size_t)(j0 + r) * (HOP_ * D_) + p0 + c];
        }
        __syncthreads();
        const float* pr = pooled + (size_t)b * (HOP_ * D_) + p0;
#pragma unroll 4
        for (int i = 0; i < 1024; i += 4) {
            float4 wv = *(const float4*)&w[jj][i];
            float4 pv = *(const float4*)&pr[i];
            acc += wv.x * pv.x + wv.y * pv.y + wv.z * pv.z + wv.w * pv.w;
        }
    }
    out[(size_t)b * D_ + j0 + jj] = acc + fcb[j0 + jj];
}

extern "C" void kernel_launch(void* const* d_in, const int* in_sizes, int n_in,
                              void* d_out, int out_size, void* d_ws, size_t ws_size,
                              hipStream_t stream) {
    const float* input = (const float*)d_in[0];
    const float* W0   = (const float*)d_in[2];
    const float* b0   = (const float*)d_in[3];
    const float* W1   = (const float*)d_in[4];
    const float* b1   = (const float*)d_in[5];
    const float* ws1  = (const float*)d_in[6];
    const float* ws2  = (const float*)d_in[7];
    const float* fc_w = (const float*)d_in[8];
    const float* fc_b = (const float*)d_in[9];

    float* out  = (float*)d_out;
    float* attn = out + (size_t)B_ * D_;
    (void)in_sizes; (void)n_in; (void)out_size;

    const int M = B_ * T_;
    char* ws = (char*)d_ws;

    // Tier A (unchunked): 181,141,632 B.  Tier B (CH=8): 80,478,336 B.
    const size_t NEED_A = 181141632ull;
    const size_t NEED_B = 80478336ull;
    const size_t NEED_FB = 100663424ull;

    if (ws_size >= NEED_B) {
        const int CHv = (ws_size >= NEED_A) ? 32 : 8;
        const int Mc = CHv * T_;
        const size_t szU = (size_t)CHv * 512 * 3072 * 2;
        const size_t szX = (size_t)CHv * 512 * 1024 * 2;
        unsigned short* Uc   = (unsigned short*)ws;        // U't [3072][Mc]
        unsigned short* xbc  = (unsigned short*)(ws + szU);
        unsigned short* x2b  = (unsigned short*)(ws + szU + szX);
        unsigned short* W0p  = (unsigned short*)(ws + szU + szX + 33554432);
        unsigned short* W1p  = W0p + 3145728;
        unsigned short* ws1p = W1p + 3145728;
        int*            len  = (int*)(ws1p + 393216);
        // alias dead U' region after the chunk loop:
        float* hbar   = (float*)ws;                    // 22,937,600
        float* alph   = (float*)(ws + 22937600);       // 524,288
        float* pooled = (float*)(ws + 23461888);       // 1,048,576 (<= 25,165,824) OK

        lengths_k<<<B_, 512, 0, stream>>>(input, len);
        convW_k<false><<<(D_ * 3 * D_) / 256, 256, 0, stream>>>(W0, W0p, D_, 3 * D_, 24, 3 * D_);
        convW_k<false><<<(D_ * 3 * D_) / 256, 256, 0, stream>>>(W1, W1p, D_, 3 * D_, 24, 3 * D_);
        convW_k<true><<<(D_ * 384) / 256, 256, 0, stream>>>(ws1, ws1p, D_, 384, 3, HID_);

        for (int c0 = 0; c0 < B_; c0 += CHv) {
            const float* inC = input + (size_t)c0 * T_ * D_;
            convX_k<<<(Mc * D_ / 4) / 256, 256, 0, stream>>>(inC, xbc);
            // Layer 1 (U't holds raw preactivations transposed; sigmoid+bias in scan)
            gemm_mfma<0><<<dim3(24, Mc / 128), 256, 0, stream>>>(xbc, W0p, Uc, D_, 24, Mc);
            sru_scan_seg<<<CHv * 16, 512, 0, stream>>>(Uc, b0, xbc, xbc, Mc);
            // Layer 2
            gemm_mfma<0><<<dim3(24, Mc / 128), 256, 0, stream>>>(xbc, W1p, Uc, D_, 24, Mc);
            sru_scan_seg<<<CHv * 16, 512, 0, stream>>>(
                Uc, b1, xbc, x2b + (size_t)c0 * T_ * D_, Mc);
        }

        // hbar = tanh(x2 @ ws1^T) over full M (U' region now dead -> hbar)
        gemm_mfma<1><<<dim3(3, M / 128), 256, 0, stream>>>(x2b, ws1p, hbar, D_, 3, HID_);

        alphas_k<<<M / 256, 256, 0, stream>>>(hbar, ws2, alph);
        softmax_k<<<B_ * HOP_, 256, 0, stream>>>(alph, len, attn);
        pooled_bf_k<<<B_ * 4, 256, 0, stream>>>(attn, x2b, pooled);
        fc_k<<<D_ / 8, 256, 0, stream>>>(pooled, fc_w, fc_b, out);
        return;
    }

    // ---- fallback: chunked fp32 (round-2 proven) ----
    if (ws_size < NEED_FB) return;

    float* U    = (float*)ws;
    float* x1c  = (float*)(ws + 25165824);
    float* x2   = (float*)(ws + 33554432);
    int*   len  = (int*)(ws + 100663296);
    float* hbar   = (float*)ws;
    float* alph   = (float*)(ws + 22937600);
    float* pooled = (float*)(ws + 23461888);

    lengths_k<<<B_, 512, 0, stream>>>(input, len);

    const int Mc = CH_ * T_;
    for (int c0 = 0; c0 < B_; c0 += CH_) {
        const float* inC = input + (size_t)c0 * T_ * D_;
        float* x2C = x2 + (size_t)c0 * T_ * D_;
        gemm64<false, false><<<dim3(3 * D_ / 64, Mc / 64), 256, 0, stream>>>(
            inC, W0, U, Mc, 3 * D_, D_);
        sru_scan<<<CH_ * D_ / 256, 256, 0, stream>>>(U, b0, inC, x1c);
        gemm64<false, false><<<dim3(3 * D_ / 64, Mc / 64), 256, 0, stream>>>(
            x1c, W1, U, Mc, 3 * D_, D_);
        sru_scan<<<CH_ * D_ / 256, 256, 0, stream>>>(U, b1, x1c, x2C);
    }

    gemm64<true, true><<<dim3((HID_ + 63) / 64, M / 64), 256, 0, stream>>>(
        x2, ws1, hbar, M, HID_, D_);
    alphas_k<<<M / 256, 256, 0, stream>>>(hbar, ws2, alph);
    softmax_k<<<B_ * HOP_, 256, 0, stream>>>(alph, len, attn);
    pooled_k<<<B_ * 4, 256, 0, stream>>>(attn, x2, pooled);
    fc_k<<<D_ / 8, 256, 0, stream>>>(pooled, fc_w, fc_b, out);
}

// Round 7
// 828.835 us; speedup vs baseline: 1.2526x; 1.2526x over previous
//
#include <hip/hip_runtime.h>
#include <hip/hip_bf16.h>

#define B_ 32
#define T_ 512
#define D_ 1024
#define HOP_ 8
#define HID_ 350
#define NEGV -1e30f
#define CH_ 4  // batches per chunk (fp32 fallback path)

typedef __bf16 v8bf __attribute__((ext_vector_type(8)));
typedef float  v4f  __attribute__((ext_vector_type(4)));

__device__ __forceinline__ float fast_sigmoid(float x) {
    return 1.0f / (1.0f + __expf(-x));
}
__device__ __forceinline__ float fast_tanh(float x) {
    return 1.0f - 2.0f / (__expf(2.0f * x) + 1.0f);
}
__device__ __forceinline__ float bf2f(unsigned short u) {
    unsigned x = ((unsigned)u) << 16;
    float f;
    __builtin_memcpy(&f, &x, 4);
    return f;
}
__device__ __forceinline__ unsigned short f2bf(float v) {
    __hip_bfloat16 h = __float2bfloat16(v);
    unsigned short u;
    __builtin_memcpy(&u, &h, 2);
    return u;
}

// ---------------- lengths ----------------
__global__ __launch_bounds__(512) void lengths_k(const float* __restrict__ input,
                                                 int* __restrict__ len) {
    int b = blockIdx.x;
    int t = threadIdx.x;
    int z = (input[((size_t)b * T_ + t) * D_] == 0.0f) ? 1 : 0;
    __shared__ int cnt;
    if (t == 0) cnt = 0;
    __syncthreads();
    unsigned long long m = __ballot(z);
    if ((t & 63) == 0) atomicAdd(&cnt, __popcll(m));
    __syncthreads();
    if (t == 0) len[b] = T_ - cnt;
}

// =================== FAST PATH (bf16 MFMA) ===================

// fp32 -> bf16 rowmajor copy (vector 4)
__global__ __launch_bounds__(256) void convX_k(const float* __restrict__ in,
                                               unsigned short* __restrict__ out) {
    int i = (blockIdx.x * 256 + threadIdx.x) * 4;
    float4 v = *(const float4*)&in[i];
    out[i + 0] = f2bf(v.x);
    out[i + 1] = f2bf(v.y);
    out[i + 2] = f2bf(v.z);
    out[i + 3] = f2bf(v.w);
}

// weight -> tiled bf16 layout [kb][nb][n:128][k:32]  (4096 elems per tile)
// NT=false: W is (K,N) row-major. NT=true: W is (Nreal,K) row-major, zero-pad n>=Nreal.
template <bool NT>
__global__ __launch_bounds__(256) void convW_k(const float* __restrict__ W,
                                               unsigned short* __restrict__ Wp,
                                               int K, int N, int nT, int Nreal) {
    int o = blockIdx.x * 256 + threadIdx.x;
    int tile = o >> 12;          // 128*32 = 4096 elems per tile
    int within = o & 4095;
    int n_l = within >> 5, k_l = within & 31;
    int kb = tile / nT, nbb = tile % nT;
    int n = nbb * 128 + n_l, k = kb * 32 + k_l;
    float v = 0.f;
    if (NT) {
        if (n < Nreal) v = W[(size_t)n * K + k];
    } else {
        v = W[(size_t)k * N + n];
    }
    Wp[o] = f2bf(v);
}

// MFMA GEMM: C = A(M,K) @ B(K,N), 128x128 tile, BK=32, 4 waves of 64x64.
// EPI 0: raw bf16 store of the 128x128 tile via LDS transpose -> U' row-major [m][3072].
// EPI 1: tanh epilogue -> fp32 C [m][n] (stride Nstore), guard col < Nstore.
template <int EPI>
__global__ __launch_bounds__(256) void gemm_mfma(
    const unsigned short* __restrict__ A,
    const unsigned short* __restrict__ Bp,
    void* __restrict__ C,
    int K, int nT, int Nstore) {
    __shared__ __align__(16) char smem[34816];  // staging 16 KB / C-tile 34 KB
    unsigned short* As = (unsigned short*)smem;
    unsigned short* Bs = (unsigned short*)(smem + 8192);
    const int tid = threadIdx.x;
    const int lane = tid & 63;
    const int wid = __builtin_amdgcn_readfirstlane(tid >> 6);
    const int wm = wid & 1, wn = wid >> 1;
    const int m0 = blockIdx.y * 128;
    const int n0 = blockIdx.x * 128;
    const int nb = blockIdx.x;
    const int quad = lane >> 4;
    const int l15 = lane & 15;

    v4f acc[4][4];
#pragma unroll
    for (int i = 0; i < 4; ++i)
#pragma unroll
        for (int j = 0; j < 4; ++j) acc[i][j] = (v4f)(0.f);

    const int nKB = K >> 5;
    for (int kb = 0; kb < nKB; ++kb) {
        __syncthreads();
        // stage A: 128 rows x 32 k; granule g (16B) -> row g>>2, kpart g&3
#pragma unroll
        for (int p = 0; p < 2; ++p) {
            int g = p * 256 + wid * 64 + lane;
            const unsigned short* gp = A + (size_t)(m0 + (g >> 2)) * K + kb * 32 + (g & 3) * 8;
            int ldsOff = (p * 256 + wid * 64) * 16;
            __builtin_amdgcn_global_load_lds(
                (const __attribute__((address_space(1))) void*)gp,
                (__attribute__((address_space(3))) void*)((char*)As + ldsOff),
                16, 0, 0);
        }
        // stage B: linear copy of pre-tiled 8KB block
        const unsigned short* bt = Bp + (size_t)(kb * nT + nb) * (128 * 32);
#pragma unroll
        for (int p = 0; p < 2; ++p) {
            int g = p * 256 + wid * 64 + lane;
            const unsigned short* gp = bt + g * 8;
            int ldsOff = (p * 256 + wid * 64) * 16;
            __builtin_amdgcn_global_load_lds(
                (const __attribute__((address_space(1))) void*)gp,
                (__attribute__((address_space(3))) void*)((char*)Bs + ldsOff),
                16, 0, 0);
        }
        __syncthreads();
        v8bf af[4], bfr[4];
#pragma unroll
        for (int mi = 0; mi < 4; ++mi)
            af[mi] = *(const v8bf*)&As[(wm * 64 + mi * 16 + l15) * 32 + quad * 8];
#pragma unroll
        for (int ni = 0; ni < 4; ++ni)
            bfr[ni] = *(const v8bf*)&Bs[(wn * 64 + ni * 16 + l15) * 32 + quad * 8];
#pragma unroll
        for (int mi = 0; mi < 4; ++mi)
#pragma unroll
            for (int ni = 0; ni < 4; ++ni)
                acc[mi][ni] = __builtin_amdgcn_mfma_f32_16x16x32_bf16(
                    af[mi], bfr[ni], acc[mi][ni], 0, 0, 0);
    }

    if (EPI == 0) {
        // LDS transpose epilogue: Ct row-major [128 m][136] (pad 8 shorts)
        __syncthreads();
        unsigned short* Ct = (unsigned short*)smem;
#pragma unroll
        for (int ni = 0; ni < 4; ++ni) {
            int n_l = wn * 64 + ni * 16 + l15;
#pragma unroll
            for (int mi = 0; mi < 4; ++mi) {
                int m_l = wm * 64 + mi * 16 + quad * 4;
                v4f cc = acc[mi][ni];
#pragma unroll
                for (int r = 0; r < 4; ++r)
                    Ct[(m_l + r) * 136 + n_l] = f2bf(cc[r]);
            }
        }
        __syncthreads();
        int row = tid >> 1;
        int colH = (tid & 1) << 6;
        unsigned short* gdst = (unsigned short*)C + (size_t)(m0 + row) * 3072 + n0 + colH;
        const unsigned short* lsrc = Ct + row * 136 + colH;
#pragma unroll
        for (int i = 0; i < 8; ++i) {
            uint4 v = *(const uint4*)(lsrc + i * 8);
            *(uint4*)(gdst + i * 8) = v;
        }
    } else {
        const int baseM = m0 + wm * 64;
        const int baseN = n0 + wn * 64;
        float* Cf = (float*)C;
#pragma unroll
        for (int ni = 0; ni < 4; ++ni) {
            int j = baseN + ni * 16 + l15;
            if (j < Nstore) {
#pragma unroll
                for (int mi = 0; mi < 4; ++mi) {
                    int m = baseM + mi * 16 + quad * 4;
                    v4f c = acc[mi][ni];
#pragma unroll
                    for (int r = 0; r < 4; ++r)
                        Cf[(size_t)(m + r) * Nstore + j] = fast_tanh(c[r]);
                }
            }
        }
    }
}

// Segmented SRU scan, register-cached. U' row-major [m][3072], raw preacts.
// Block: 512 threads = 32 d x 16 segments (32 t each); grid = nB * 32 d-chunks.
// Phase A caches xt + sigmoid(f) in 64 VGPRs -> phase C reads only r + residual.
__global__ __launch_bounds__(512) void sru_scan_seg(
    const unsigned short* __restrict__ Up,
    const float* __restrict__ bias,
    const unsigned short* __restrict__ xres,
    unsigned short* __restrict__ xout) {
    int b = blockIdx.x >> 5;
    int d0 = (blockIdx.x & 31) << 5;
    int dl = threadIdx.x & 31;
    int s = threadIdx.x >> 5;   // 0..15
    int d = d0 + dl;
    float bf = bias[d], br = bias[D_ + d];
    const unsigned short* Ub = Up + (size_t)b * T_ * 3072 + d;
    const int t0 = s * 32;

    float xt[32], fv[32];
    float Aa = 1.f, Bv = 0.f;
#pragma unroll
    for (int j = 0; j < 32; ++j) {
        const unsigned short* u = Ub + (size_t)(t0 + j) * 3072;
        xt[j] = bf2f(u[0]);
        float f = fast_sigmoid(bf2f(u[1024]) + bf);
        fv[j] = f;
        Aa *= f;
        Bv = f * Bv + (1.f - f) * xt[j];
    }
    __shared__ float Asm[16][32], Bsm[16][32], cinS[16][32];
    Asm[s][dl] = Aa;
    Bsm[s][dl] = Bv;
    __syncthreads();
    if (threadIdx.x < 32) {
        float c = 0.f;
#pragma unroll
        for (int ss = 0; ss < 16; ++ss) {
            cinS[ss][threadIdx.x] = c;
            c = Asm[ss][threadIdx.x] * c + Bsm[ss][threadIdx.x];
        }
    }
    __syncthreads();
    float c = cinS[s][dl];
    const unsigned short* xr = xres + (size_t)b * T_ * D_ + d;
    unsigned short* ob = xout + (size_t)b * T_ * D_ + d;
#pragma unroll
    for (int j = 0; j < 32; ++j) {
        int t = t0 + j;
        float r = fast_sigmoid(bf2f(Ub[(size_t)t * 3072 + 2048]) + br);
        c = fv[j] * c + (1.f - fv[j]) * xt[j];
        float xv = bf2f(xr[(size_t)t * D_]);
        float o = r * fast_tanh(c) + (1.f - r) * xv;
        ob[(size_t)t * D_] = f2bf(o);
    }
}

// =================== FALLBACK PATH (fp32, chunked; round-2 proven) ===================

template <bool BT, bool DO_TANH>
__global__ __launch_bounds__(256) void gemm64(const float* __restrict__ A,
                                              const float* __restrict__ Bm,
                                              float* __restrict__ C,
                                              int M, int N, int K) {
    __shared__ float Asm[16][64];
    __shared__ float Bsm[16][64];
    const int tid = threadIdx.x;
    const int tx = tid & 15;
    const int ty = tid >> 4;
    const int m0 = blockIdx.y * 64;
    const int n0 = blockIdx.x * 64;
    float acc[4][4] = {};
    const int ar = tid >> 2;
    const int ac = (tid & 3) << 2;

    for (int k0 = 0; k0 < K; k0 += 16) {
        {
            float4 v = *(const float4*)&A[(size_t)(m0 + ar) * K + k0 + ac];
            Asm[ac + 0][ar] = v.x; Asm[ac + 1][ar] = v.y;
            Asm[ac + 2][ar] = v.z; Asm[ac + 3][ar] = v.w;
        }
        if (!BT) {
            int kk = tid >> 4;
            int c4 = (tid & 15) << 2;
            float4 v = *(const float4*)&Bm[(size_t)(k0 + kk) * N + n0 + c4];
            Bsm[kk][c4 + 0] = v.x; Bsm[kk][c4 + 1] = v.y;
            Bsm[kk][c4 + 2] = v.z; Bsm[kk][c4 + 3] = v.w;
        } else {
            int nn = tid >> 2;
            int kk = (tid & 3) << 2;
            int row = n0 + nn;
            if (row < N) {
                float4 v = *(const float4*)&Bm[(size_t)row * K + k0 + kk];
                Bsm[kk + 0][nn] = v.x; Bsm[kk + 1][nn] = v.y;
                Bsm[kk + 2][nn] = v.z; Bsm[kk + 3][nn] = v.w;
            } else {
                Bsm[kk + 0][nn] = 0.f; Bsm[kk + 1][nn] = 0.f;
                Bsm[kk + 2][nn] = 0.f; Bsm[kk + 3][nn] = 0.f;
            }
        }
        __syncthreads();
#pragma unroll
        for (int kk = 0; kk < 16; ++kk) {
            float4 a = *(const float4*)&Asm[kk][ty << 2];
            float4 b = *(const float4*)&Bsm[kk][tx << 2];
            float am[4] = {a.x, a.y, a.z, a.w};
            float bm[4] = {b.x, b.y, b.z, b.w};
#pragma unroll
            for (int i = 0; i < 4; ++i)
#pragma unroll
                for (int j = 0; j < 4; ++j)
                    acc[i][j] += am[i] * bm[j];
        }
        __syncthreads();
    }
#pragma unroll
    for (int i = 0; i < 4; ++i) {
        int row = m0 + (ty << 2) + i;
#pragma unroll
        for (int j = 0; j < 4; ++j) {
            int col = n0 + (tx << 2) + j;
            if (col < N) {
                float v = acc[i][j];
                if (DO_TANH) v = fast_tanh(v);
                C[(size_t)row * N + col] = v;
            }
        }
    }
}

__global__ __launch_bounds__(256) void sru_scan(const float* __restrict__ U,
                                                const float* __restrict__ bias,
                                                const float* __restrict__ xin,
                                                float* __restrict__ xout) {
    int idx = blockIdx.x * 256 + threadIdx.x;
    int b = idx >> 10;
    int d = idx & (D_ - 1);
    float bfv = bias[d], br = bias[D_ + d];
    float c = 0.0f;
    const float* Ub = U + (size_t)b * T_ * (3 * D_);
    const float* xb = xin + (size_t)b * T_ * D_;
    float* ob = xout + (size_t)b * T_ * D_;
    for (int t = 0; t < T_; t += 8) {
        float ux[8], uf[8], ur[8], xv[8];
#pragma unroll
        for (int j = 0; j < 8; ++j) {
            const float* u = Ub + (size_t)(t + j) * (3 * D_);
            ux[j] = u[d];
            uf[j] = u[D_ + d];
            ur[j] = u[2 * D_ + d];
            xv[j] = xb[(size_t)(t + j) * D_ + d];
        }
#pragma unroll
        for (int j = 0; j < 8; ++j) {
            float f = fast_sigmoid(uf[j] + bfv);
            float r = fast_sigmoid(ur[j] + br);
            c = f * c + (1.0f - f) * ux[j];
            ob[(size_t)(t + j) * D_ + d] = r * fast_tanh(c) + (1.0f - r) * xv[j];
        }
    }
}

// =================== shared tail kernels ===================

__global__ __launch_bounds__(256) void alphas_k(const float* __restrict__ hbar,
                                                const float* __restrict__ ws2,
                                                float* __restrict__ alph) {
    __shared__ float w[HOP_][352];
    for (int i = threadIdx.x; i < HOP_ * HID_; i += 256)
        w[i / HID_][i % HID_] = ws2[i];
    __syncthreads();
    int bt = blockIdx.x * 256 + threadIdx.x;
    const float* hr = hbar + (size_t)bt * HID_;
    float acc[HOP_] = {};
    for (int h = 0; h < HID_; ++h) {
        float hv = hr[h];
#pragma unroll
        for (int k = 0; k < HOP_; ++k) acc[k] += w[k][h] * hv;
    }
    float* ar = alph + (size_t)bt * HOP_;
#pragma unroll
    for (int k = 0; k < HOP_; ++k) ar[k] = acc[k];
}

__global__ __launch_bounds__(256) void softmax_k(const float* __restrict__ alph,
                                                 const int* __restrict__ len,
                                                 float* __restrict__ attn) {
    int b = blockIdx.x >> 3, k = blockIdx.x & 7;
    int L = len[b];
    int t0 = threadIdx.x, t1 = threadIdx.x + 256;
    float v0 = (t0 >= L) ? NEGV : alph[((size_t)b * T_ + t0) * HOP_ + k];
    float v1 = (t1 >= L) ? NEGV : alph[((size_t)b * T_ + t1) * HOP_ + k];
    __shared__ float redm[4];
    __shared__ float reds[4];
    float m = fmaxf(v0, v1);
#pragma unroll
    for (int off = 32; off; off >>= 1) m = fmaxf(m, __shfl_xor(m, off));
    if ((threadIdx.x & 63) == 0) redm[threadIdx.x >> 6] = m;
    __syncthreads();
    m = fmaxf(fmaxf(redm[0], redm[1]), fmaxf(redm[2], redm[3]));
    float e0 = __expf(v0 - m), e1 = __expf(v1 - m);
    float s = e0 + e1;
#pragma unroll
    for (int off = 32; off; off >>= 1) s += __shfl_xor(s, off);
    if ((threadIdx.x & 63) == 0) reds[threadIdx.x >> 6] = s;
    __syncthreads();
    s = reds[0] + reds[1] + reds[2] + reds[3];
    float inv = 1.0f / s;
    float* ar = attn + ((size_t)b * HOP_ + k) * T_;
    ar[t0] = e0 * inv;
    ar[t1] = e1 * inv;
}

// pooled from bf16 x2 (normal [m][d] layout)
__global__ __launch_bounds__(256) void pooled_bf_k(const float* __restrict__ attn,
                                                   const unsigned short* __restrict__ x2b,
                                                   float* __restrict__ pooled) {
    __shared__ float at[HOP_][T_];
    int b = blockIdx.x >> 2;
    int d0 = (blockIdx.x & 3) * 256;
    for (int i = threadIdx.x; i < HOP_ * T_; i += 256)
        at[i >> 9][i & (T_ - 1)] = attn[(size_t)b * HOP_ * T_ + i];
    __syncthreads();
    int d = d0 + threadIdx.x;
    float acc[HOP_] = {};
    const unsigned short* xb = x2b + (size_t)b * T_ * D_ + d;
    for (int t = 0; t < T_; ++t) {
        float xv = bf2f(xb[(size_t)t * D_]);
#pragma unroll
        for (int k = 0; k < HOP_; ++k) acc[k] += at[k][t] * xv;
    }
#pragma unroll
    for (int k = 0; k < HOP_; ++k)
        pooled[((size_t)b * HOP_ + k) * D_ + d] = acc[k];
}

// pooled from fp32 x2 (fallback)
__global__ __launch_bounds__(256) void pooled_k(const float* __restrict__ attn,
                                                const float* __restrict__ x2,
                                                float* __restrict__ pooled) {
    __shared__ float at[HOP_][T_];
    int b = blockIdx.x >> 2;
    int d0 = (blockIdx.x & 3) * 256;
    for (int i = threadIdx.x; i < HOP_ * T_; i += 256)
        at[i >> 9][i & (T_ - 1)] = attn[(size_t)b * HOP_ * T_ + i];
    __syncthreads();
    int d = d0 + threadIdx.x;
    float acc[HOP_] = {};
    const float* xb = x2 + (size_t)b * T_ * D_ + d;
    for (int t = 0; t < T_; ++t) {
        float xv = xb[(size_t)t * D_];
#pragma unroll
        for (int k = 0; k < HOP_; ++k) acc[k] += at[k][t] * xv;
    }
#pragma unroll
    for (int k = 0; k < HOP_; ++k)
        pooled[((size_t)b * HOP_ + k) * D_ + d] = acc[k];
}

__global__ __launch_bounds__(256) void fc_k(const float* __restrict__ pooled,
                                            const float* __restrict__ fcw,
                                            const float* __restrict__ fcb,
                                            float* __restrict__ out) {
    __shared__ float w[8][1028];
    int j0 = blockIdx.x * 8;
    int b = threadIdx.x >> 3, jj = threadIdx.x & 7;
    float acc = 0.0f;
    for (int p0 = 0; p0 < HOP_ * D_; p0 += 1024) {
        __syncthreads();
        for (int i = threadIdx.x * 4; i < 8 * 1024; i += 256 * 4) {
            int r = i >> 10, c = i & 1023;
            *(float4*)&w[r][c] = *(const float4*)&fcw[(size_t)(j0 + r) * (HOP_ * D_) + p0 + c];
        }
        __syncthreads();
        const float* pr = pooled + (size_t)b * (HOP_ * D_) + p0;
#pragma unroll 4
        for (int i = 0; i < 1024; i += 4) {
            float4 wv = *(const float4*)&w[jj][i];
            float4 pv = *(const float4*)&pr[i];
            acc += wv.x * pv.x + wv.y * pv.y + wv.z * pv.z + wv.w * pv.w;
        }
    }
    out[(size_t)b * D_ + j0 + jj] = acc + fcb[j0 + jj];
}

extern "C" void kernel_launch(void* const* d_in, const int* in_sizes, int n_in,
                              void* d_out, int out_size, void* d_ws, size_t ws_size,
                              hipStream_t stream) {
    const float* input = (const float*)d_in[0];
    const float* W0   = (const float*)d_in[2];
    const float* b0   = (const float*)d_in[3];
    const float* W1   = (const float*)d_in[4];
    const float* b1   = (const float*)d_in[5];
    const float* ws1  = (const float*)d_in[6];
    const float* ws2  = (const float*)d_in[7];
    const float* fc_w = (const float*)d_in[8];
    const float* fc_b = (const float*)d_in[9];

    float* out  = (float*)d_out;
    float* attn = out + (size_t)B_ * D_;
    (void)in_sizes; (void)n_in; (void)out_size;

    const int M = B_ * T_;
    char* ws = (char*)d_ws;

    // Tier A (unchunked): 181,141,632 B.  Tier B (CH=8): 80,478,336 B.
    const size_t NEED_A = 181141632ull;
    const size_t NEED_B = 80478336ull;
    const size_t NEED_FB = 100663424ull;

    if (ws_size >= NEED_B) {
        const int CHv = (ws_size >= NEED_A) ? 32 : 8;
        const int Mc = CHv * T_;
        const size_t szU = (size_t)CHv * 512 * 3072 * 2;
        const size_t szX = (size_t)CHv * 512 * 1024 * 2;
        unsigned short* Uc   = (unsigned short*)ws;        // U' row-major [Mc][3072]
        unsigned short* xbc  = (unsigned short*)(ws + szU);
        unsigned short* x2b  = (unsigned short*)(ws + szU + szX);
        unsigned short* W0p  = (unsigned short*)(ws + szU + szX + 33554432);
        unsigned short* W1p  = W0p + 3145728;
        unsigned short* ws1p = W1p + 3145728;
        int*            len  = (int*)(ws1p + 393216);
        // alias dead U' region after the chunk loop:
        float* hbar   = (float*)ws;                    // 22,937,600
        float* alph   = (float*)(ws + 22937600);       // 524,288
        float* pooled = (float*)(ws + 23461888);       // 1,048,576 (<= 25,165,824) OK

        lengths_k<<<B_, 512, 0, stream>>>(input, len);
        convW_k<false><<<(D_ * 3 * D_) / 256, 256, 0, stream>>>(W0, W0p, D_, 3 * D_, 24, 3 * D_);
        convW_k<false><<<(D_ * 3 * D_) / 256, 256, 0, stream>>>(W1, W1p, D_, 3 * D_, 24, 3 * D_);
        convW_k<true><<<(D_ * 384) / 256, 256, 0, stream>>>(ws1, ws1p, D_, 384, 3, HID_);

        for (int c0 = 0; c0 < B_; c0 += CHv) {
            const float* inC = input + (size_t)c0 * T_ * D_;
            convX_k<<<(Mc * D_ / 4) / 256, 256, 0, stream>>>(inC, xbc);
            // Layer 1 (U' holds raw preactivations; sigmoid+bias applied in scan)
            gemm_mfma<0><<<dim3(24, Mc / 128), 256, 0, stream>>>(xbc, W0p, Uc, D_, 24, 0);
            sru_scan_seg<<<CHv * 32, 512, 0, stream>>>(Uc, b0, xbc, xbc);
            // Layer 2
            gemm_mfma<0><<<dim3(24, Mc / 128), 256, 0, stream>>>(xbc, W1p, Uc, D_, 24, 0);
            sru_scan_seg<<<CHv * 32, 512, 0, stream>>>(
                Uc, b1, xbc, x2b + (size_t)c0 * T_ * D_);
        }

        // hbar = tanh(x2 @ ws1^T) over full M (U' region now dead -> hbar)
        gemm_mfma<1><<<dim3(3, M / 128), 256, 0, stream>>>(x2b, ws1p, hbar, D_, 3, HID_);

        alphas_k<<<M / 256, 256, 0, stream>>>(hbar, ws2, alph);
        softmax_k<<<B_ * HOP_, 256, 0, stream>>>(alph, len, attn);
        pooled_bf_k<<<B_ * 4, 256, 0, stream>>>(attn, x2b, pooled);
        fc_k<<<D_ / 8, 256, 0, stream>>>(pooled, fc_w, fc_b, out);
        return;
    }

    // ---- fallback: chunked fp32 (round-2 proven) ----
    if (ws_size < NEED_FB) return;

    float* U    = (float*)ws;
    float* x1c  = (float*)(ws + 25165824);
    float* x2   = (float*)(ws + 33554432);
    int*   len  = (int*)(ws + 100663296);
    float* hbar   = (float*)ws;
    float* alph   = (float*)(ws + 22937600);
    float* pooled = (float*)(ws + 23461888);

    lengths_k<<<B_, 512, 0, stream>>>(input, len);

    const int Mc = CH_ * T_;
    for (int c0 = 0; c0 < B_; c0 += CH_) {
        const float* inC = input + (size_t)c0 * T_ * D_;
        float* x2C = x2 + (size_t)c0 * T_ * D_;
        gemm64<false, false><<<dim3(3 * D_ / 64, Mc / 64), 256, 0, stream>>>(
            inC, W0, U, Mc, 3 * D_, D_);
        sru_scan<<<CH_ * D_ / 256, 256, 0, stream>>>(U, b0, inC, x1c);
        gemm64<false, false><<<dim3(3 * D_ / 64, Mc / 64), 256, 0, stream>>>(
            x1c, W1, U, Mc, 3 * D_, D_);
        sru_scan<<<CH_ * D_ / 256, 256, 0, stream>>>(U, b1, x1c, x2C);
    }

    gemm64<true, true><<<dim3((HID_ + 63) / 64, M / 64), 256, 0, stream>>>(
        x2, ws1, hbar, M, HID_, D_);
    alphas_k<<<M / 256, 256, 0, stream>>>(hbar, ws2, alph);
    softmax_k<<<B_ * HOP_, 256, 0, stream>>>(alph, len, attn);
    pooled_k<<<B_ * 4, 256, 0, stream>>>(attn, x2, pooled);
    fc_k<<<D_ / 8, 256, 0, stream>>>(pooled, fc_w, fc_b, out);
}